// Round 4
// baseline (674.778 us; speedup 1.0000x reference)
//
#include <hip/hip_runtime.h>
#include <stdint.h>

#define FP8_MAX 448.0f
#define BSQ 128          // quantization block size
#define BM 256
#define BN 256
#define BK 128           // K-step = one scale block
#define NKB 32           // K / BSQ

typedef int   i32x4  __attribute__((ext_vector_type(4)));
typedef int   i32x8  __attribute__((ext_vector_type(8)));
typedef float f32x4v __attribute__((ext_vector_type(4)));
typedef float f32x16 __attribute__((ext_vector_type(16)));

typedef const __attribute__((address_space(1))) uint8_t* gptr_t;
typedef __attribute__((address_space(3))) uint8_t* lptr_t;

// 3-bit granule hash: 32-row fragment b128 reads spread evenly over all
// 8 granule-columns -> bank-minimal (verified: SQ_LDS_BANK_CONFLICT == 0).
__device__ __forceinline__ int hsw(int row) { return (row ^ (row >> 3)) & 7; }

// ---------------- activation quantization: per (row, 128-block) ----------------
// scales written TRANSPOSED: sxT[kb*M + row]  (linear lane x 4B gather in GEMM)
__global__ void act_quant_kernel(const float* __restrict__ x,
                                 uint8_t* __restrict__ xq,
                                 float* __restrict__ sxT,
                                 int M, int K) {
    int gid  = blockIdx.x * blockDim.x + threadIdx.x;
    int wave = gid >> 6;
    int lane = threadIdx.x & 63;
    int nkb  = K / BSQ;
    int row  = wave / nkb;
    int kb   = wave - row * nkb;
    if (row >= M) return;

    const float2 v = *(const float2*)(x + (size_t)row * K + kb * BSQ + lane * 2);
    float am = fmaxf(fabsf(v.x), fabsf(v.y));
#pragma unroll
    for (int off = 32; off >= 1; off >>= 1)
        am = fmaxf(am, __shfl_xor(am, off));

    float s = am / FP8_MAX;                    // matches reference: amax/448 in fp32
    if (lane == 0) sxT[(size_t)kb * M + row] = s;

    float q0 = (am > 0.f) ? v.x / s : 0.f;     // fp32 IEEE division, then RNE->e4m3
    float q1 = (am > 0.f) ? v.y / s : 0.f;
    int packed = __builtin_amdgcn_cvt_pk_fp8_f32(q0, q1, 0, false);
    *(uint16_t*)(xq + (size_t)row * K + kb * BSQ + lane * 2) = (uint16_t)(packed & 0xffff);
}

// ---------------- weight cast fp32(fp8-representable) -> e4m3 bytes ----------------
__global__ void weight_quant_kernel(const float* __restrict__ w,
                                    uint8_t* __restrict__ wq, size_t n) {
    size_t i = ((size_t)blockIdx.x * blockDim.x + threadIdx.x) * 4;
    if (i >= n) return;
    float4 v = *(const float4*)(w + i);
    int lo = __builtin_amdgcn_cvt_pk_fp8_f32(v.x, v.y, 0, false);
    int hi = __builtin_amdgcn_cvt_pk_fp8_f32(v.z, v.w, 0, false);
    *(uint32_t*)(wq + i) = (uint32_t)((lo & 0xffff) | (hi << 16));
}

// ---------------- 256^2 phase-split MX GEMM with DERIVED COUNTED vmcnt ----------------
// Chunks per step (staging tile kb+1): S0 = B rows 0..127 + scale row (3 ops),
// S1 = B rows 128..255 (2), S2 = A rows {0..63,128..191} (2), S3 = A rows
// {64..127,192..255} (2). 9 vmem ops/wave/step, issued one chunk per phase.
// Waits: ph1 vmcnt(5) [S3 of cur resident], ph3 vmcnt(2) [S0',S1',S2' resident].
__global__ __launch_bounds__(512, 2)
void fp8_gemm_mx8(const uint8_t* __restrict__ Aq,   // [M][K] e4m3
                  const uint8_t* __restrict__ Bq,   // [N][K] e4m3
                  const float*  __restrict__ sxT,   // [K/128][M]
                  const float*  __restrict__ swg,   // [N/128][K/128]
                  float* __restrict__ out,          // [M][N]
                  int M, int N, int K) {
    __shared__ uint8_t As[2][BM * BK];   // 2 x 32 KB
    __shared__ uint8_t Bs[2][BN * BK];   // 2 x 32 KB
    __shared__ float   sxs[2][BM];       // 2 x 1 KB

    const int tid  = threadIdx.x;
    const int lane = tid & 63;
    const int wid  = tid >> 6;
    const int wy   = wid >> 2;           // 0..1  (128 A-rows each)
    const int wx   = wid & 3;            // 0..3  (64 B-rows each)
    const int fl   = lane & 31;
    const int hi   = lane >> 5;

    // XCD-aware bijective swizzle (nwg = 1024, divisible by 8)
    const int nwg = gridDim.x;
    const int cpx = nwg >> 3;
    const int swz = (blockIdx.x & 7) * cpx + (blockIdx.x >> 3);
    const int nbx = N / BN;
    const int brow = (swz / nbx) * BM;
    const int bcol = (swz % nbx) * BN;

    auto CHUNK = [&](int q, int buf, int kb) {
        if (q < 2) {                               // B half q
#pragma unroll
            for (int r = 0; r < 2; ++r) {
                int slot = r * 512 + tid;          // 1024 16B-slots/half
                int row  = q * 128 + (slot >> 3);
                int g    = (slot & 7) ^ hsw(row);
                const uint8_t* gB = Bq + (size_t)(bcol + row) * K + kb * BK + g * 16;
                __builtin_amdgcn_global_load_lds((gptr_t)gB,
                    (lptr_t)(Bs[buf] + (row & ~7) * BK), 16, 0, 0);
            }
            if (q == 0 && lane < 32) {             // 256 scale floats, 32/wave
                const float* gs = sxT + (size_t)kb * M + brow + wid * 32 + lane;
                __builtin_amdgcn_global_load_lds((gptr_t)(const uint8_t*)gs,
                    (lptr_t)(sxs[buf] + wid * 32), 4, 0, 0);
            }
        } else {                                   // A rows for fm = 2(q-2)..2(q-2)+1
#pragma unroll
            for (int r = 0; r < 2; ++r) {
                int slot = r * 512 + tid;
                int rp   = slot >> 3;              // 0..127
                int row  = (rp & 63) + ((rp & 64) << 1) + ((q == 3) ? 64 : 0);
                int g    = (slot & 7) ^ hsw(row);
                const uint8_t* gA = Aq + (size_t)(brow + row) * K + kb * BK + g * 16;
                __builtin_amdgcn_global_load_lds((gptr_t)gA,
                    (lptr_t)(As[buf] + (row & ~7) * BK), 16, 0, 0);
            }
        }
    };

    const f32x16 zz = {0.f,0.f,0.f,0.f, 0.f,0.f,0.f,0.f,
                       0.f,0.f,0.f,0.f, 0.f,0.f,0.f,0.f};
    f32x16 acc[4][2];
#pragma unroll
    for (int i = 0; i < 4; ++i)
#pragma unroll
        for (int j = 0; j < 2; ++j) acc[i][j] = zz;

    // prologue: stage tile 0 fully; gate S0,S1,S2 (S3 gated at ph1 of kb=0)
    CHUNK(0, 0, 0); CHUNK(1, 0, 0); CHUNK(2, 0, 0); CHUNK(3, 0, 0);
    asm volatile("s_waitcnt vmcnt(2)" ::: "memory");
    __builtin_amdgcn_s_barrier();
    asm volatile("" ::: "memory");

    for (int kb = 0; kb < NKB; ++kb) {
        const int cur = kb & 1;
        const uint8_t* Ab = As[cur];
        const uint8_t* Bb = Bs[cur];
        const float*   Sb = sxs[cur];
        const bool pf = (kb + 1 < NKB);
        const float sw = swg[(size_t)((bcol >> 7) + (wx >> 1)) * NKB + kb];

        // B fragments for the whole step (8 b128), reused by all 4 phases
        i32x8 bfr[2][2];
#pragma unroll
        for (int fn = 0; fn < 2; ++fn) {
            int row = wx * 64 + fn * 32 + fl;
            int hh  = hsw(row);
            const uint8_t* base = Bb + row * BK;
#pragma unroll
            for (int kh = 0; kh < 2; ++kh) {
                int g0 = kh * 4 + hi * 2;
                i32x4 lo = *(const i32x4*)(base + (((g0    ) ^ hh) << 4));
                i32x4 h4 = *(const i32x4*)(base + (((g0 + 1) ^ hh) << 4));
                bfr[fn][kh] = (i32x8){lo.x, lo.y, lo.z, lo.w, h4.x, h4.y, h4.z, h4.w};
            }
        }

#pragma unroll
        for (int fm = 0; fm < 4; ++fm) {
            // ---- issue this phase's LDS reads + next-tile chunk, then gate ----
            int arow = wy * 128 + fm * 32 + fl;
            int hh   = hsw(arow);
            const uint8_t* abase = Ab + arow * BK;
            i32x8 afr[2];
#pragma unroll
            for (int kh = 0; kh < 2; ++kh) {
                int g0 = kh * 4 + hi * 2;
                i32x4 lo = *(const i32x4*)(abase + (((g0    ) ^ hh) << 4));
                i32x4 h4 = *(const i32x4*)(abase + (((g0 + 1) ^ hh) << 4));
                afr[kh] = (i32x8){lo.x, lo.y, lo.z, lo.w, h4.x, h4.y, h4.z, h4.w};
            }
            f32x4v s4[4];
#pragma unroll
            for (int q = 0; q < 4; ++q) {
                s4[q] = *(const f32x4v*)&Sb[wy * 128 + fm * 32 + q * 8 + hi * 4];
                s4[q] *= sw;
            }

            if (pf) CHUNK(fm, cur ^ 1, kb + 1);

            if (fm == 1) {         // gate S3(cur) for ph2/ph3 A-reads
                if (pf) asm volatile("s_waitcnt vmcnt(5)" ::: "memory");
                else    asm volatile("s_waitcnt vmcnt(0)" ::: "memory");
            }
            if (fm == 3 && pf) {   // gate S0',S1',S2' for next step
                asm volatile("s_waitcnt vmcnt(2)" ::: "memory");
            }
            __builtin_amdgcn_s_barrier();
            asm volatile("" ::: "memory");

            __builtin_amdgcn_s_setprio(1);
            f32x16 p0 = __builtin_amdgcn_mfma_scale_f32_32x32x64_f8f6f4(
                afr[0], bfr[0][0], zz, 0, 0, 0, 127, 0, 127);
            p0 = __builtin_amdgcn_mfma_scale_f32_32x32x64_f8f6f4(
                afr[1], bfr[0][1], p0, 0, 0, 0, 127, 0, 127);
            f32x16 p1 = __builtin_amdgcn_mfma_scale_f32_32x32x64_f8f6f4(
                afr[0], bfr[1][0], zz, 0, 0, 0, 127, 0, 127);
            p1 = __builtin_amdgcn_mfma_scale_f32_32x32x64_f8f6f4(
                afr[1], bfr[1][1], p1, 0, 0, 0, 127, 0, 127);
            __builtin_amdgcn_s_setprio(0);

#pragma unroll
            for (int q = 0; q < 4; ++q)
#pragma unroll
                for (int j = 0; j < 4; ++j) {
                    acc[fm][0][q * 4 + j] += p0[q * 4 + j] * s4[q][j];
                    acc[fm][1][q * 4 + j] += p1[q * 4 + j] * s4[q][j];
                }
        }
    }

    // epilogue: C/D 32x32 layout col=lane&31, row=(reg&3)+8*(reg>>2)+4*(lane>>5)
    // nontemporal: 268MB streaming writes must not evict L3-resident B panels
#pragma unroll
    for (int fm = 0; fm < 4; ++fm)
#pragma unroll
        for (int fn = 0; fn < 2; ++fn)
#pragma unroll
            for (int q = 0; q < 4; ++q)
#pragma unroll
                for (int j = 0; j < 4; ++j) {
                    int row = brow + wy * 128 + fm * 32 + q * 8 + hi * 4 + j;
                    int col = bcol + wx * 64 + fn * 32 + fl;
                    __builtin_nontemporal_store(acc[fm][fn][q * 4 + j],
                                                &out[(size_t)row * N + col]);
                }
}

extern "C" void kernel_launch(void* const* d_in, const int* in_sizes, int n_in,
                              void* d_out, int out_size, void* d_ws, size_t ws_size,
                              hipStream_t stream) {
    const float* x   = (const float*)d_in[0];
    const float* w   = (const float*)d_in[1];
    const float* wsi = (const float*)d_in[2];
    float* out = (float*)d_out;

    const int K = 4096;
    const int M = in_sizes[0] / K;       // 4096
    const int N = in_sizes[1] / K;       // 16384

    uint8_t* xq  = (uint8_t*)d_ws;                      // M*K bytes
    uint8_t* wq  = xq + (size_t)M * K;                  // N*K bytes
    float*   sxT = (float*)(wq + (size_t)N * K);        // (K/128)*M floats

    int waves = M * (K / BSQ);
    act_quant_kernel<<<dim3(waves / 4), dim3(256), 0, stream>>>(x, xq, sxT, M, K);

    size_t wn = (size_t)N * K;
    weight_quant_kernel<<<dim3((unsigned)(wn / 4 / 256)), dim3(256), 0, stream>>>(w, wq, wn);

    dim3 grid((N / BN) * (M / BM));      // 1024, 1D for swizzle
    fp8_gemm_mx8<<<grid, dim3(512), 0, stream>>>(xq, wq, sxT, wsi, out, M, N, K);
}

// Round 5
// 458.380 us; speedup vs baseline: 1.4721x; 1.4721x over previous
//
#include <hip/hip_runtime.h>
#include <stdint.h>

#define FP8_MAX 448.0f
#define BSQ 128          // quantization block size
#define TM 128
#define TN 128
#define NKB 32           // K / BSQ

typedef int   i32x4  __attribute__((ext_vector_type(4)));
typedef int   i32x8  __attribute__((ext_vector_type(8)));
typedef float f32x4v __attribute__((ext_vector_type(4)));
typedef float f32x16 __attribute__((ext_vector_type(16)));

typedef const __attribute__((address_space(1))) uint8_t* gptr_t;
typedef __attribute__((address_space(3))) uint8_t* lptr_t;

// 3-bit granule hash: 32-row fragment b128 reads spread evenly over all
// 8 granule-columns -> bank-minimal (verified: 0 conflicts in rounds 3/4).
__device__ __forceinline__ int hsw(int row) { return (row ^ (row >> 3)) & 7; }

// ---------------- activation quantization: per (row, 128-block) ----------------
// scales written TRANSPOSED: sxT[kb*M + row]  (lane-linear gather in GEMM stage)
__global__ void act_quant_kernel(const float* __restrict__ x,
                                 uint8_t* __restrict__ xq,
                                 float* __restrict__ sxT,
                                 int M, int K) {
    int gid  = blockIdx.x * blockDim.x + threadIdx.x;
    int wave = gid >> 6;
    int lane = threadIdx.x & 63;
    int nkb  = K / BSQ;
    int row  = wave / nkb;
    int kb   = wave - row * nkb;
    if (row >= M) return;

    const float2 v = *(const float2*)(x + (size_t)row * K + kb * BSQ + lane * 2);
    float am = fmaxf(fabsf(v.x), fabsf(v.y));
#pragma unroll
    for (int off = 32; off >= 1; off >>= 1)
        am = fmaxf(am, __shfl_xor(am, off));

    float s = am / FP8_MAX;                    // matches reference: amax/448 in fp32
    if (lane == 0) sxT[(size_t)kb * M + row] = s;

    float q0 = (am > 0.f) ? v.x / s : 0.f;     // fp32 IEEE division, then RNE->e4m3
    float q1 = (am > 0.f) ? v.y / s : 0.f;
    int packed = __builtin_amdgcn_cvt_pk_fp8_f32(q0, q1, 0, false);
    *(uint16_t*)(xq + (size_t)row * K + kb * BSQ + lane * 2) = (uint16_t)(packed & 0xffff);
}

// ---------------- weight cast fp32(fp8-representable) -> e4m3 bytes ----------------
__global__ void weight_quant_kernel(const float* __restrict__ w,
                                    uint8_t* __restrict__ wq, size_t n) {
    size_t i = ((size_t)blockIdx.x * blockDim.x + threadIdx.x) * 4;
    if (i >= n) return;
    float4 v = *(const float4*)(w + i);
    int lo = __builtin_amdgcn_cvt_pk_fp8_f32(v.x, v.y, 0, false);
    int hi = __builtin_amdgcn_cvt_pk_fp8_f32(v.z, v.w, 0, false);
    *(uint32_t*)(wq + i) = (uint32_t)((lo & 0xffff) | (hi << 16));
}

// ---------------- 128^2 dbuf MX GEMM: STAGE(kb+1) issued before compute(kb) ----------------
// y[m,n] = sum_kb sx[m,kb]*sw[nb,kb] * dot_fp8(x[m,kb*128:+128], w[n,kb*128:+128])
__global__ __launch_bounds__(256, 2)
void fp8_gemm_mx(const uint8_t* __restrict__ Aq,   // [M][K] e4m3
                 const uint8_t* __restrict__ Bq,   // [N][K] e4m3
                 const float*  __restrict__ sxT,   // [K/128][M]  (transposed)
                 const float*  __restrict__ swg,   // [N/128][K/128]
                 float* __restrict__ out,          // [M][N]
                 int M, int N, int K) {
    __shared__ uint8_t As[2][TM * BSQ];      // 2 x 16 KB, granule-swizzled rows
    __shared__ uint8_t Bs[2][TN * BSQ];      // 2 x 16 KB
    __shared__ float   sxs[2][TM];           // 2 x 0.5 KB raw sx row

    const int tid  = threadIdx.x;
    const int lane = tid & 63;
    const int wid  = tid >> 6;
    const int brow = blockIdx.y * TM;
    const int bcol = blockIdx.x * TN;
    const int nb   = bcol >> 7;

    const int wy = wid >> 1, wx = wid & 1;   // 2x2 wave grid, 64x64 per wave
    const int fl = lane & 31, hi = lane >> 5;

    // staging: LDS dest linear, global SOURCE pre-swizzled (involution)
    auto STAGE = [&](int buf, int kb) {
#pragma unroll
        for (int r = 0; r < 4; ++r) {
            int slot = r * 256 + tid;          // 0..1023 16B-slots
            int row  = slot >> 3;              // 0..127
            int g    = (slot & 7) ^ hsw(row);
            const uint8_t* gA = Aq + (size_t)(brow + row) * K + kb * BSQ + g * 16;
            const uint8_t* gB = Bq + (size_t)(bcol + row) * K + kb * BSQ + g * 16;
            __builtin_amdgcn_global_load_lds((gptr_t)gA,
                (lptr_t)(As[buf] + (slot & ~63) * 16), 16, 0, 0);
            __builtin_amdgcn_global_load_lds((gptr_t)gB,
                (lptr_t)(Bs[buf] + (slot & ~63) * 16), 16, 0, 0);
        }
        if (wid < 2) {                         // 128-float scale row, lane x 4B linear
            const float* gs = sxT + (size_t)kb * M + brow + wid * 64 + lane;
            __builtin_amdgcn_global_load_lds((gptr_t)(const uint8_t*)gs,
                (lptr_t)(sxs[buf] + wid * 64), 4, 0, 0);
        }
    };

    const f32x16 zz = {0.f,0.f,0.f,0.f, 0.f,0.f,0.f,0.f,
                       0.f,0.f,0.f,0.f, 0.f,0.f,0.f,0.f};
    f32x16 acc[2][2];
#pragma unroll
    for (int i = 0; i < 2; ++i)
#pragma unroll
        for (int j = 0; j < 2; ++j) acc[i][j] = zz;

    // prologue: stage kb=0, drain once (__syncthreads inserts vmcnt(0))
    STAGE(0, 0);
    __syncthreads();

    for (int kb = 0; kb < NKB; ++kb) {
        const int cur = kb & 1;
        const uint8_t* Ab = As[cur];
        const uint8_t* Bb = Bs[cur];
        const float*   Sb = sxs[cur];

        // issue next tile's loads FIRST: latency hides under this step's compute
        if (kb + 1 < NKB) STAGE(cur ^ 1, kb + 1);

        const float sw = swg[(size_t)nb * NKB + kb];   // block-uniform weight scale

        // B fragments (8 x b128), reused across fm
        i32x8 bfr[2][2];
#pragma unroll
        for (int fn = 0; fn < 2; ++fn) {
            int row = wx * 64 + fn * 32 + fl;
            int hh  = hsw(row);
            const uint8_t* base = Bb + row * BSQ;
#pragma unroll
            for (int kh = 0; kh < 2; ++kh) {
                int g0 = kh * 4 + hi * 2;
                i32x4 lo = *(const i32x4*)(base + (((g0    ) ^ hh) << 4));
                i32x4 h4 = *(const i32x4*)(base + (((g0 + 1) ^ hh) << 4));
                bfr[fn][kh] = (i32x8){lo.x, lo.y, lo.z, lo.w, h4.x, h4.y, h4.z, h4.w};
            }
        }

#pragma unroll
        for (int fm = 0; fm < 2; ++fm) {
            int arow = wy * 64 + fm * 32 + fl;
            int hh   = hsw(arow);
            const uint8_t* abase = Ab + arow * BSQ;
            i32x8 afr[2];
#pragma unroll
            for (int kh = 0; kh < 2; ++kh) {
                int g0 = kh * 4 + hi * 2;
                i32x4 lo = *(const i32x4*)(abase + (((g0    ) ^ hh) << 4));
                i32x4 h4 = *(const i32x4*)(abase + (((g0 + 1) ^ hh) << 4));
                afr[kh] = (i32x8){lo.x, lo.y, lo.z, lo.w, h4.x, h4.y, h4.z, h4.w};
            }
            // per-row scales (broadcast b128 reads) x block-uniform sw
            f32x4v s4[4];
#pragma unroll
            for (int q = 0; q < 4; ++q) {
                s4[q] = *(const f32x4v*)&Sb[wy * 64 + fm * 32 + q * 8 + hi * 4];
                s4[q] *= sw;
            }

#pragma unroll
            for (int fn = 0; fn < 2; ++fn) {
                // unit HW scales (e8m0 127 -> x1.0); exact fp32 fold below
                f32x16 p = __builtin_amdgcn_mfma_scale_f32_32x32x64_f8f6f4(
                    afr[0], bfr[fn][0], zz, 0, 0, 0, 127, 0, 127);
                p = __builtin_amdgcn_mfma_scale_f32_32x32x64_f8f6f4(
                    afr[1], bfr[fn][1], p, 0, 0, 0, 127, 0, 127);
#pragma unroll
                for (int q = 0; q < 4; ++q)
#pragma unroll
                    for (int j = 0; j < 4; ++j)
                        acc[fm][fn][q * 4 + j] += p[q * 4 + j] * s4[q][j];
            }
        }

        // single drain point per step: next tile resident before buffer swap.
        // At 2 blocks/CU the co-resident block computes through this wait.
        __syncthreads();
    }

    // epilogue: C/D 32x32 layout col=lane&31, row=(reg&3)+8*(reg>>2)+4*(lane>>5)
    // nontemporal: 268MB streaming writes must not evict L3-resident fp8 panels
#pragma unroll
    for (int fm = 0; fm < 2; ++fm)
#pragma unroll
        for (int fn = 0; fn < 2; ++fn)
#pragma unroll
            for (int q = 0; q < 4; ++q)
#pragma unroll
                for (int j = 0; j < 4; ++j) {
                    int row = brow + wy * 64 + fm * 32 + q * 8 + hi * 4 + j;
                    int col = bcol + wx * 64 + fn * 32 + fl;
                    __builtin_nontemporal_store(acc[fm][fn][q * 4 + j],
                                                &out[(size_t)row * N + col]);
                }
}

extern "C" void kernel_launch(void* const* d_in, const int* in_sizes, int n_in,
                              void* d_out, int out_size, void* d_ws, size_t ws_size,
                              hipStream_t stream) {
    const float* x   = (const float*)d_in[0];
    const float* w   = (const float*)d_in[1];
    const float* wsi = (const float*)d_in[2];
    float* out = (float*)d_out;

    const int K = 4096;
    const int M = in_sizes[0] / K;       // 4096
    const int N = in_sizes[1] / K;       // 16384

    uint8_t* xq  = (uint8_t*)d_ws;                      // M*K bytes
    uint8_t* wq  = xq + (size_t)M * K;                  // N*K bytes
    float*   sxT = (float*)(wq + (size_t)N * K);        // (K/128)*M floats

    int waves = M * (K / BSQ);
    act_quant_kernel<<<dim3(waves / 4), dim3(256), 0, stream>>>(x, xq, sxT, M, K);

    size_t wn = (size_t)N * K;
    weight_quant_kernel<<<dim3((unsigned)(wn / 4 / 256)), dim3(256), 0, stream>>>(w, wq, wn);

    dim3 grid(N / TN, M / TM);
    fp8_gemm_mx<<<grid, dim3(256), 0, stream>>>(xq, wq, sxT, wsi, out, M, N, K);
}